// Round 6
// baseline (471.414 us; speedup 1.0000x reference)
//
#include <hip/hip_runtime.h>

#define BS   64
#define Q    300
#define K    91
#define T    4096
#define TPER 64
#define M    300   // Hungarian cols (queries)
#define NR   64    // Hungarian rows (targets per batch)
#define WS_STRIDE 304

typedef float __attribute__((ext_vector_type(4))) f32x4;

// ---------------------------------------------------------------------------
// shared cost formula (fast rcp: ~1ulp on O(1) terms, well within tolerance)
// ---------------------------------------------------------------------------
__device__ __forceinline__ float cost_entry(const float4 pb, const float4 tb,
                                            const float prob)
{
    const float px0 = pb.x - pb.z * 0.5f, py0 = pb.y - pb.w * 0.5f;
    const float px1 = pb.x + pb.z * 0.5f, py1 = pb.y + pb.w * 0.5f;
    const float parea = (px1 - px0) * (py1 - py0);
    const float tx0 = tb.x - tb.z * 0.5f, ty0 = tb.y - tb.w * 0.5f;
    const float tx1 = tb.x + tb.z * 0.5f, ty1 = tb.y + tb.w * 0.5f;
    const float tarea = (tx1 - tx0) * (ty1 - ty0);
    const float bb = fabsf(pb.x - tb.x) + fabsf(pb.y - tb.y)
                   + fabsf(pb.z - tb.z) + fabsf(pb.w - tb.w);
    const float iw = fmaxf(fminf(px1, tx1) - fmaxf(px0, tx0), 0.f);
    const float ih = fmaxf(fminf(py1, ty1) - fmaxf(py0, ty0), 0.f);
    const float inter = iw * ih;
    const float uni   = parea + tarea - inter;
    const float iou   = inter * __builtin_amdgcn_rcpf(uni);
    const float cw  = fmaxf(fmaxf(px1, tx1) - fminf(px0, tx0), 0.f);
    const float ch  = fmaxf(fmaxf(py1, ty1) - fminf(py0, ty0), 0.f);
    const float carea = cw * ch;
    const float giou  = iou - (carea - uni) * __builtin_amdgcn_rcpf(carea);
    return 5.0f * bb - prob - 2.0f * giou;
}

// ---------------------------------------------------------------------------
// cost kernel (STANDALONE: no doubles in scope -> low VGPR -> high occupancy)
// 256 threads (4 waves), 4 (b,q) rows per block, 1200 blocks.
// Per thread: 4 chunks x 4 targets x 4 rows = 64 entries.
// ---------------------------------------------------------------------------
__global__ __launch_bounds__(256) void cost_kernel(
    const float* __restrict__ probs,    // [BS,Q,K]
    const float* __restrict__ pboxes,   // [BS,Q,4]
    const float* __restrict__ tboxes,   // [T,4]
    const int*   __restrict__ tlabels,  // [T]
    float* __restrict__ C)              // [BS,Q,T]
{
    __shared__ __align__(16) float sprob4[K][4];   // [class][row]
    const int tid = threadIdx.x;
    const int bq0 = blockIdx.x * 4;
    for (int idx = tid; idx < 4 * K; idx += 256) {
        const int k = idx >> 2, r = idx & 3;
        sprob4[k][r] = probs[(size_t)(bq0 + r) * K + k];
    }
    float4 pbr[4];
#pragma unroll
    for (int r = 0; r < 4; ++r) pbr[r] = ((const float4*)pboxes)[bq0 + r];
    __syncthreads();

    const float4* tbv = (const float4*)tboxes;
    const int4*   lbv = (const int4*)tlabels;

#pragma unroll 1
    for (int c = 0; c < 4; ++c) {
        const int t0 = (c << 10) + (tid << 2);
        const int4 lb = lbv[t0 >> 2];
        const int labs[4] = { lb.x, lb.y, lb.z, lb.w };
        float4 tb[4];
        float4 pr[4];
#pragma unroll
        for (int k = 0; k < 4; ++k) {
            tb[k] = tbv[t0 + k];
            pr[k] = *(const float4*)sprob4[labs[k]];
        }
#pragma unroll
        for (int r = 0; r < 4; ++r) {
            float o[4];
#pragma unroll
            for (int k = 0; k < 4; ++k) {
                const float prk = (r == 0) ? pr[k].x : (r == 1) ? pr[k].y
                                : (r == 2) ? pr[k].z : pr[k].w;
                o[k] = cost_entry(pbr[r], tb[k], prk);
            }
            f32x4 v = { o[0], o[1], o[2], o[3] };
            __builtin_nontemporal_store(
                v, (f32x4*)&C[(size_t)(bq0 + r) * T + t0]);
        }
    }
}

// ---------------------------------------------------------------------------
// hungarian kernel (STANDALONE; logic byte-identical to proven rounds 3/5):
// one wave per batch; register-resident JV (e-maxx order-exact) + greedy
// dual-feasible init (u[i]=rowmin, claim argmin col). Slice recomputed from
// inputs (no dependency on C). lane l owns cols 5l..5l+4; lane l holds u[l+1].
// ---------------------------------------------------------------------------
__global__ __launch_bounds__(64) void hungarian_kernel(
    const float* __restrict__ probs, const float* __restrict__ pboxes,
    const float* __restrict__ tboxes, const int* __restrict__ tlabels,
    float* __restrict__ ws, float* __restrict__ pred_out,
    float* __restrict__ tgt_out)
{
    __shared__ int p[M + 1];
    __shared__ int way[M + 1];
    __shared__ int rargArr[NR];
    const int b = blockIdx.x;
    float* __restrict__ wslice = ws + (size_t)b * NR * WS_STRIDE;
    const int tid = threadIdx.x;
    const bool lv = (tid < 60);
    const int c0 = lv ? 5 * tid : 0;

    // ---- recompute this batch's 64x300 slice: cost[i=target][j=query]
    //      fused with per-row (min, argmin) wave reduce
    float4 pbx[5];
#pragma unroll
    for (int s = 0; s < 5; ++s)
        pbx[s] = ((const float4*)pboxes)[b * Q + c0 + s];

    float rmin_f = 1e30f; int rarg = 0;      // valid on lane == row after loop
#pragma unroll 1
    for (int i = 0; i < NR; ++i) {
        const float4 tb = ((const float4*)tboxes)[b * TPER + i];
        const int lab = tlabels[b * TPER + i];
        const size_t pbase = (size_t)(b * Q + c0) * K + lab;
        float vals[5];
        float lmin = 1e30f; int lidx = 0x7fffffff;
#pragma unroll
        for (int s = 0; s < 5; ++s) {
            const float pr = probs[pbase + (size_t)s * K];
            vals[s] = cost_entry(pbx[s], tb, pr);
            if (lv && vals[s] < lmin) { lmin = vals[s]; lidx = c0 + s; }
        }
        if (lv) {
#pragma unroll
            for (int s = 0; s < 5; ++s)
                wslice[i * WS_STRIDE + c0 + s] = vals[s];
        }
        float rv = lv ? lmin : 1e30f; int ri = lidx;
#pragma unroll
        for (int off = 32; off > 0; off >>= 1) {
            const float ov = __shfl_xor(rv, off);
            const int   oi = __shfl_xor(ri, off);
            if (ov < rv || (ov == rv && oi < ri)) { rv = ov; ri = oi; }
        }
        if (tid == i) { rmin_f = rv; rarg = ri; }
    }
    double u_reg = (double)rmin_f;           // u[tid+1] = rowmin (dual-feasible, v=0)

    rargArr[tid] = rarg;
    for (int j = tid; j <= M; j += 64) p[j] = 0;
    __syncthreads();                         // also drains wslice stores (vmcnt)

    // ---- greedy claim in row order (serial on lane 0, then broadcast mask)
    unsigned long long m0 = 0ull;
    if (tid == 0) {
#pragma unroll 1
        for (int r = 0; r < NR; ++r) {
            const int ac = rargArr[r] + 1;
            if (p[ac] == 0) { p[ac] = r + 1; m0 |= 1ull << r; }
        }
    }
    __syncthreads();
    const unsigned long long matchedRows = __shfl(m0, 0);

    // ---- JV state
    double v_[5], minv_[5];
#pragma unroll
    for (int s = 0; s < 5; ++s) v_[s] = 0.0;
    const unsigned used0 = lv ? 0u : 0x1fu;

#pragma unroll 1
    for (int i = 1; i <= NR; ++i) {
        if ((matchedRows >> (i - 1)) & 1ull) continue;   // greedily matched
        if (tid == 0) p[0] = i;
        unsigned usedmask = used0;
        bool inTree = false;
#pragma unroll
        for (int s = 0; s < 5; ++s) minv_[s] = 1e18;
        int i0 = i, j0 = 0;
        float crow[5];
        {
            const float* rp = wslice + (size_t)(i0 - 1) * WS_STRIDE + c0;
#pragma unroll
            for (int s = 0; s < 5; ++s) crow[s] = rp[s];
        }
        int guard = 0;
        while (true) {
            if (tid == i0 - 1) inTree = true;
            const double ui0 = __shfl(u_reg, i0 - 1);
            // scan my 5 cols
            double lmin = 1e18; int lidx = 0x7fffffff;
#pragma unroll
            for (int s = 0; s < 5; ++s) {
                if (!((usedmask >> s) & 1u)) {
                    const double cj = (double)crow[s] - ui0 - v_[s];
                    if (cj < minv_[s]) { minv_[s] = cj; way[c0 + s + 1] = j0; }
                    if (minv_[s] < lmin) { lmin = minv_[s]; lidx = c0 + s; }
                }
            }
            // wave64 (min,val) reduce, tie -> lowest col (numpy argmin)
            double rv = lmin; int ri = lidx;
#pragma unroll
            for (int off = 32; off > 0; off >>= 1) {
                const double ov = __shfl_xor(rv, off);
                const int    oi = __shfl_xor(ri, off);
                if (ov < rv || (ov == rv && oi < ri)) { rv = ov; ri = oi; }
            }
            const double delta = rv;
            const int c1 = ri, j1 = c1 + 1;
            const int i0n = p[j1];                 // LDS broadcast read
            // prefetch next row while we update potentials
            float crow2[5];
            if (i0n) {
                const float* rp2 = wslice + (size_t)(i0n - 1) * WS_STRIDE + c0;
#pragma unroll
                for (int s = 0; s < 5; ++s) crow2[s] = rp2[s];
            }
            if (inTree) u_reg += delta;            // u[p[j]] += delta for used j
#pragma unroll
            for (int s = 0; s < 5; ++s) {
                if ((usedmask >> s) & 1u) v_[s] -= delta;
                else                      minv_[s] -= delta;
            }
            if (lv && c1 >= c0 && c1 < c0 + 5) usedmask |= 1u << (c1 - c0);
            j0 = j1;
            if (!i0n || ++guard > 512) break;
            i0 = i0n;
#pragma unroll
            for (int s = 0; s < 5; ++s) crow[s] = crow2[s];
        }
        __syncthreads();
        if (tid == 0) {                            // augment
            int jj = j0;
            while (jj) { const int jn = way[jj]; p[jj] = p[jn]; jj = jn; }
        }
        __syncthreads();
    }

    // ---- emit matches in column order
    int cnt = 0;
#pragma unroll
    for (int s = 0; s < 5; ++s)
        if (lv && p[c0 + s + 1] > 0) ++cnt;
    int incl = cnt;
#pragma unroll
    for (int off = 1; off < 64; off <<= 1) {
        const int t = __shfl_up(incl, off);
        if (tid >= off) incl += t;
    }
    int pos = incl - cnt;
#pragma unroll
    for (int s = 0; s < 5; ++s) {
        if (lv) {
            const int pi = p[c0 + s + 1];
            if (pi > 0) {
                pred_out[b * TPER + pos] = (float)(c0 + s);
                tgt_out [b * TPER + pos] = (float)(pi - 1);
                ++pos;
            }
        }
    }
}

// ===========================================================================
// fallback (round-1 proven path, no workspace) if ws_size is too small
// ===========================================================================
__global__ __launch_bounds__(64) void hungarian_kernel_fb(
    const float* __restrict__ C, float* __restrict__ pred_out,
    float* __restrict__ tgt_out)
{
    __shared__ float  cost[NR * M];
    __shared__ double v[M + 1], minv[M + 1], u[NR + 1];
    __shared__ int    p[M + 1], way[M + 1];
    __shared__ unsigned char used[M + 1];
    const int b = blockIdx.x;
    const int tid = threadIdx.x;
    const double INF = 1e18;
    for (int e = tid; e < NR * M; e += 64) {
        const int q = e >> 6, i = e & 63;
        cost[i * M + q] = C[(size_t)b * Q * T + (size_t)q * T + b * TPER + i];
    }
    for (int j = tid; j <= M; j += 64) { v[j] = 0.0; p[j] = 0; }
    for (int j = tid; j <= NR; j += 64) u[j] = 0.0;
    __syncthreads();
    for (int i = 1; i <= NR; ++i) {
        if (tid == 0) p[0] = i;
        for (int j = tid; j <= M; j += 64) { minv[j] = INF; used[j] = 0; }
        __syncthreads();
        int j0 = 0;
        while (true) {
            if (tid == 0) used[j0] = 1;
            __syncthreads();
            const int    i0  = p[j0];
            const double ui0 = u[i0];
            const float* crow = &cost[(i0 - 1) * M];
            double lmin = INF; int lidx = M + 1;
            for (int j = tid + 1; j <= M; j += 64) {
                if (!used[j]) {
                    double mv = minv[j];
                    const double cj = (double)crow[j - 1] - ui0 - v[j];
                    if (cj < mv) { mv = cj; minv[j] = cj; way[j] = j0; }
                    if (mv < lmin) { lmin = mv; lidx = j; }
                }
            }
#pragma unroll
            for (int off = 32; off > 0; off >>= 1) {
                const double oval = __shfl_down(lmin, off);
                const int    oidx = __shfl_down(lidx, off);
                if (oval < lmin || (oval == lmin && oidx < lidx)) { lmin = oval; lidx = oidx; }
            }
            const int    j1    = __shfl(lidx, 0);
            const double delta = __shfl(lmin, 0);
            __syncthreads();
            for (int j = tid; j <= M; j += 64) {
                if (used[j]) { u[p[j]] += delta; v[j] -= delta; }
                else          minv[j] -= delta;
            }
            __syncthreads();
            j0 = j1;
            if (p[j0] == 0) break;
        }
        if (tid == 0) {
            int jj = j0;
            while (jj) { const int j1 = way[jj]; p[jj] = p[j1]; jj = j1; }
        }
        __syncthreads();
    }
    if (tid == 0) {
        int kk = 0;
        for (int j = 1; j <= M; ++j) {
            if (p[j] > 0) {
                pred_out[b * TPER + kk] = (float)(j - 1);
                tgt_out [b * TPER + kk] = (float)(p[j] - 1);
                ++kk;
            }
        }
    }
}

extern "C" void kernel_launch(void* const* d_in, const int* in_sizes, int n_in,
                              void* d_out, int out_size, void* d_ws, size_t ws_size,
                              hipStream_t stream) {
    const float* probs   = (const float*)d_in[0];   // [64,300,91]
    const float* pboxes  = (const float*)d_in[1];   // [64,300,4]
    const float* tboxes  = (const float*)d_in[2];   // [4096,4]
    const int*   tlabels = (const int*)  d_in[3];   // [4096]

    float* C    = (float*)d_out;                    // [64,300,4096]
    float* pred = C + (size_t)BS * Q * T;           // [64,64] as float
    float* tgt  = pred + (size_t)BS * TPER;         // [64,64] as float

    const size_t ws_needed = (size_t)BS * NR * WS_STRIDE * sizeof(float);
    if (ws_size >= ws_needed) {
        // hungarian first (independent of C) -> clean per-kernel attribution,
        // and its input reads see an unpolluted L2.
        hipLaunchKernelGGL(hungarian_kernel, dim3(BS), dim3(64), 0, stream,
                           probs, pboxes, tboxes, tlabels, (float*)d_ws, pred, tgt);
        hipLaunchKernelGGL(cost_kernel, dim3(BS * Q / 4), dim3(256), 0, stream,
                           probs, pboxes, tboxes, tlabels, C);
    } else {
        hipLaunchKernelGGL(cost_kernel, dim3(BS * Q / 4), dim3(256), 0, stream,
                           probs, pboxes, tboxes, tlabels, C);
        hipLaunchKernelGGL(hungarian_kernel_fb, dim3(BS), dim3(64), 0, stream,
                           C, pred, tgt);
    }
}

// Round 7
// 369.823 us; speedup vs baseline: 1.2747x; 1.2747x over previous
//
#include <hip/hip_runtime.h>

#define BS   64
#define Q    300
#define K    91
#define T    4096
#define TPER 64
#define M    300   // Hungarian cols (queries)
#define NR   64    // Hungarian rows (targets per batch)
#define WS_STRIDE 304

typedef float __attribute__((ext_vector_type(4))) f32x4;

// ---------------------------------------------------------------------------
// cost formula (fast rcp: ~1ulp on O(1) terms, within tolerance) — r5-proven
// ---------------------------------------------------------------------------
__device__ __forceinline__ float cost_entry(const float4 pb, const float4 tb,
                                            const float prob)
{
    const float px0 = pb.x - pb.z * 0.5f, py0 = pb.y - pb.w * 0.5f;
    const float px1 = pb.x + pb.z * 0.5f, py1 = pb.y + pb.w * 0.5f;
    const float parea = (px1 - px0) * (py1 - py0);
    const float tx0 = tb.x - tb.z * 0.5f, ty0 = tb.y - tb.w * 0.5f;
    const float tx1 = tb.x + tb.z * 0.5f, ty1 = tb.y + tb.w * 0.5f;
    const float tarea = (tx1 - tx0) * (ty1 - ty0);
    const float bb = fabsf(pb.x - tb.x) + fabsf(pb.y - tb.y)
                   + fabsf(pb.z - tb.z) + fabsf(pb.w - tb.w);
    const float iw = fmaxf(fminf(px1, tx1) - fmaxf(px0, tx0), 0.f);
    const float ih = fmaxf(fminf(py1, ty1) - fmaxf(py0, ty0), 0.f);
    const float inter = iw * ih;
    const float uni   = parea + tarea - inter;
    const float iou   = inter * __builtin_amdgcn_rcpf(uni);
    const float cw  = fmaxf(fmaxf(px1, tx1) - fminf(px0, tx0), 0.f);
    const float ch  = fmaxf(fmaxf(py1, ty1) - fminf(py0, ty0), 0.f);
    const float carea = cw * ch;
    const float giou  = iou - (carea - uni) * __builtin_amdgcn_rcpf(carea);
    return 5.0f * bb - prob - 2.0f * giou;
}

// hoisted variant: identical op tree, pred/target xyxy+areas precomputed
__device__ __forceinline__ float cost_entry_h(
    const float4 pb, float px0, float py0, float px1, float py1, float parea,
    const float4 tb, float tx0, float ty0, float tx1, float ty1, float tarea,
    float prob)
{
    const float bb = fabsf(pb.x - tb.x) + fabsf(pb.y - tb.y)
                   + fabsf(pb.z - tb.z) + fabsf(pb.w - tb.w);
    const float iw = fmaxf(fminf(px1, tx1) - fmaxf(px0, tx0), 0.f);
    const float ih = fmaxf(fminf(py1, ty1) - fmaxf(py0, ty0), 0.f);
    const float inter = iw * ih;
    const float uni   = parea + tarea - inter;
    const float iou   = inter * __builtin_amdgcn_rcpf(uni);
    const float cw  = fmaxf(fmaxf(px1, tx1) - fminf(px0, tx0), 0.f);
    const float ch  = fmaxf(fmaxf(py1, ty1) - fminf(py0, ty0), 0.f);
    const float carea = cw * ch;
    const float giou  = iou - (carea - uni) * __builtin_amdgcn_rcpf(carea);
    return 5.0f * bb - prob - 2.0f * giou;
}

// ---------------------------------------------------------------------------
// cost tile: 256 threads, 4 (b,q) rows x 4096 targets; hoisted invariants
// ---------------------------------------------------------------------------
__device__ void cost_tile(int cb, const float* __restrict__ probs,
                          const float* __restrict__ pboxes,
                          const float* __restrict__ tboxes,
                          const int*   __restrict__ tlabels,
                          float* __restrict__ C)
{
    __shared__ __align__(16) float sprob4[K][4];   // [class][row]
    const int tid = threadIdx.x;
    const int bq0 = cb * 4;
    for (int idx = tid; idx < 4 * K; idx += 256) {
        const int k = idx >> 2, r = idx & 3;
        sprob4[k][r] = probs[(size_t)(bq0 + r) * K + k];
    }
    float4 pbr[4];
    float px0[4], py0[4], px1[4], py1[4], pare[4];
#pragma unroll
    for (int r = 0; r < 4; ++r) {
        const float4 pb = ((const float4*)pboxes)[bq0 + r];
        pbr[r] = pb;
        px0[r] = pb.x - pb.z * 0.5f;  py0[r] = pb.y - pb.w * 0.5f;
        px1[r] = pb.x + pb.z * 0.5f;  py1[r] = pb.y + pb.w * 0.5f;
        pare[r] = (px1[r] - px0[r]) * (py1[r] - py0[r]);
    }
    __syncthreads();

    const float4* tbv = (const float4*)tboxes;
    const int4*   lbv = (const int4*)tlabels;

#pragma unroll 1
    for (int c = 0; c < 4; ++c) {
        const int t0 = (c << 10) + (tid << 2);
        const int4 lb = lbv[t0 >> 2];
        const int labs[4] = { lb.x, lb.y, lb.z, lb.w };
        float4 tb[4], pr[4];
#pragma unroll
        for (int k = 0; k < 4; ++k) {
            tb[k] = tbv[t0 + k];
            pr[k] = *(const float4*)sprob4[labs[k]];
        }
        float o[4][4];
#pragma unroll
        for (int k = 0; k < 4; ++k) {
            const float tx0 = tb[k].x - tb[k].z * 0.5f, ty0 = tb[k].y - tb[k].w * 0.5f;
            const float tx1 = tb[k].x + tb[k].z * 0.5f, ty1 = tb[k].y + tb[k].w * 0.5f;
            const float tarea = (tx1 - tx0) * (ty1 - ty0);
#pragma unroll
            for (int r = 0; r < 4; ++r) {
                const float prk = (r == 0) ? pr[k].x : (r == 1) ? pr[k].y
                                : (r == 2) ? pr[k].z : pr[k].w;
                o[r][k] = cost_entry_h(pbr[r], px0[r], py0[r], px1[r], py1[r], pare[r],
                                       tb[k], tx0, ty0, tx1, ty1, tarea, prk);
            }
        }
#pragma unroll
        for (int r = 0; r < 4; ++r) {
            f32x4 v = { o[r][0], o[r][1], o[r][2], o[r][3] };
            __builtin_nontemporal_store(
                v, (f32x4*)&C[(size_t)(bq0 + r) * T + t0]);
        }
    }
}

// ---------------------------------------------------------------------------
// hungarian tile: 256 threads. All 4 waves recompute the 64x300 slice (16
// rows each) fused with per-row (min,argmin); then waves 1-3 retire and wave
// 0 runs greedy init + register-resident JV (e-maxx order, r5-proven) with
// NO barriers (single wave: __threadfence_block = s_waitcnt suffices).
// Cross-lane argmin uses packed u64 (minv>=0 so double bits are order-
// isomorphic; low 9 bits = col, auto lowest-col tie-break; ~1e-16 delta
// truncation is assignment-invariant for unique optima).
// ---------------------------------------------------------------------------
__device__ void hungarian_tile(int b, const float* __restrict__ probs,
                               const float* __restrict__ pboxes,
                               const float* __restrict__ tboxes,
                               const int* __restrict__ tlabels,
                               float* __restrict__ wslice,
                               float* __restrict__ pred_out,
                               float* __restrict__ tgt_out)
{
    __shared__ int   p[M + 1];
    __shared__ int   way[M + 1];
    __shared__ int   rargArr[NR];
    __shared__ float rminArr[NR];
    const int tid  = threadIdx.x;
    const int wav  = tid >> 6;
    const int lane = tid & 63;
    const bool lv  = (lane < 60);
    const int c0   = lv ? 5 * lane : 0;

    // ---- recompute slice cost[i=target][j=query], 16 rows per wave,
    //      fused per-row (min, argmin) wave reduce
    float4 pbx[5];
#pragma unroll
    for (int s = 0; s < 5; ++s)
        pbx[s] = ((const float4*)pboxes)[b * Q + c0 + s];

    const int i0r = wav * 16;
#pragma unroll 1
    for (int i = i0r; i < i0r + 16; ++i) {
        const float4 tb = ((const float4*)tboxes)[b * TPER + i];
        const int lab = tlabels[b * TPER + i];
        const size_t pbase = (size_t)(b * Q + c0) * K + lab;
        float vals[5];
        float lmin = 1e30f; int lidx = 0x7fffffff;
#pragma unroll
        for (int s = 0; s < 5; ++s) {
            const float pr = probs[pbase + (size_t)s * K];
            vals[s] = cost_entry(pbx[s], tb, pr);
            if (lv && vals[s] < lmin) { lmin = vals[s]; lidx = c0 + s; }
        }
        if (lv) {
#pragma unroll
            for (int s = 0; s < 5; ++s)
                wslice[i * WS_STRIDE + c0 + s] = vals[s];
        }
        float rv = lv ? lmin : 1e30f; int ri = lidx;
#pragma unroll
        for (int off = 32; off > 0; off >>= 1) {
            const float ov = __shfl_xor(rv, off);
            const int   oi = __shfl_xor(ri, off);
            if (ov < rv || (ov == rv && oi < ri)) { rv = ov; ri = oi; }
        }
        if (lane == 0) { rminArr[i] = rv; rargArr[i] = ri; }
    }
    for (int j = tid; j <= M; j += 256) p[j] = 0;
    __threadfence_block();
    __syncthreads();          // slice + rmin/rarg + p visible to all waves
    if (wav != 0) return;     // wave 0 continues alone: no barriers below

    double u_reg = (double)rminArr[lane];   // u[lane+1] = rowmin (v=0 feasible)

    // ---- greedy claim in row order (serial on lane 0)
    unsigned long long m0 = 0ull;
    if (lane == 0) {
#pragma unroll 1
        for (int r = 0; r < NR; ++r) {
            const int ac = rargArr[r] + 1;
            if (p[ac] == 0) { p[ac] = r + 1; m0 |= 1ull << r; }
        }
    }
    __threadfence_block();    // lane0's p[] writes -> wave
    const unsigned long long matchedRows = __shfl(m0, 0);

    // ---- JV state
    double v_[5], minv_[5];
#pragma unroll
    for (int s = 0; s < 5; ++s) v_[s] = 0.0;
    const unsigned used0 = lv ? 0u : 0x1fu;

#pragma unroll 1
    for (int i = 1; i <= NR; ++i) {
        if ((matchedRows >> (i - 1)) & 1ull) continue;   // greedily matched
        if (lane == 0) p[0] = i;
        unsigned usedmask = used0;
        bool inTree = false;
#pragma unroll
        for (int s = 0; s < 5; ++s) minv_[s] = 1e18;
        int i0 = i, j0 = 0;
        float crow[5];
        {
            const float* rp = wslice + (size_t)(i0 - 1) * WS_STRIDE + c0;
#pragma unroll
            for (int s = 0; s < 5; ++s) crow[s] = rp[s];
        }
        int guard = 0;
        while (true) {
            if (lane == i0 - 1) inTree = true;
            const double ui0 = __shfl(u_reg, i0 - 1);
            // scan my 5 cols; build packed (minv | col)
            long long lmin64 = 0x7fffffffffffffffll;
#pragma unroll
            for (int s = 0; s < 5; ++s) {
                if (!((usedmask >> s) & 1u)) {
                    const double cj = (double)crow[s] - ui0 - v_[s];
                    if (cj < minv_[s]) { minv_[s] = cj; way[c0 + s + 1] = j0; }
                    const long long pk =
                        (__double_as_longlong(minv_[s]) & ~0x1ffll) | (c0 + s);
                    if (pk < lmin64) lmin64 = pk;
                }
            }
            // wave64 u64-min reduce (ties -> lowest col automatically)
#pragma unroll
            for (int off = 32; off > 0; off >>= 1) {
                const long long o = __shfl_xor(lmin64, off);
                if (o < lmin64) lmin64 = o;
            }
            const double delta = __longlong_as_double(lmin64 & ~0x1ffll);
            const int c1 = (int)(lmin64 & 0x1ff), j1 = c1 + 1;
            const int i0n = p[j1];                 // LDS broadcast read
            // prefetch next row while we update potentials
            float crow2[5];
            if (i0n) {
                const float* rp2 = wslice + (size_t)(i0n - 1) * WS_STRIDE + c0;
#pragma unroll
                for (int s = 0; s < 5; ++s) crow2[s] = rp2[s];
            }
            if (inTree) u_reg += delta;            // u[p[j]] += delta for used j
#pragma unroll
            for (int s = 0; s < 5; ++s) {
                if ((usedmask >> s) & 1u) v_[s] -= delta;
                else                      minv_[s] -= delta;
            }
            if (lv && c1 >= c0 && c1 < c0 + 5) usedmask |= 1u << (c1 - c0);
            j0 = j1;
            if (!i0n || ++guard > 512) break;
            i0 = i0n;
#pragma unroll
            for (int s = 0; s < 5; ++s) crow[s] = crow2[s];
        }
        __threadfence_block();    // way[] writes -> lane 0
        if (lane == 0) {          // augment
            int jj = j0;
            while (jj) { const int jn = way[jj]; p[jj] = p[jn]; jj = jn; }
        }
        __threadfence_block();    // p[] writes -> wave
    }

    // ---- emit matches in column order (wave 0)
    int cnt = 0;
#pragma unroll
    for (int s = 0; s < 5; ++s)
        if (lv && p[c0 + s + 1] > 0) ++cnt;
    int incl = cnt;
#pragma unroll
    for (int off = 1; off < 64; off <<= 1) {
        const int t = __shfl_up(incl, off);
        if (lane >= off) incl += t;
    }
    int pos = incl - cnt;
#pragma unroll
    for (int s = 0; s < 5; ++s) {
        if (lv) {
            const int pi = p[c0 + s + 1];
            if (pi > 0) {
                pred_out[b * TPER + pos] = (float)(c0 + s);
                tgt_out [b * TPER + pos] = (float)(pi - 1);
                ++pos;
            }
        }
    }
}

// ---------------------------------------------------------------------------
// fused kernel: blocks 0..63 hungarian, rest cost (proven-concurrent layout)
// ---------------------------------------------------------------------------
__global__ __launch_bounds__(256) void fused_kernel(
    const float* __restrict__ probs, const float* __restrict__ pboxes,
    const float* __restrict__ tboxes, const int* __restrict__ tlabels,
    float* __restrict__ C, float* __restrict__ pred_out,
    float* __restrict__ tgt_out, float* __restrict__ ws)
{
    const int bid = blockIdx.x;
    if (bid < BS)
        hungarian_tile(bid, probs, pboxes, tboxes, tlabels,
                       ws + (size_t)bid * NR * WS_STRIDE, pred_out, tgt_out);
    else
        cost_tile(bid - BS, probs, pboxes, tboxes, tlabels, C);
}

__global__ __launch_bounds__(256) void cost_kernel(
    const float* __restrict__ probs, const float* __restrict__ pboxes,
    const float* __restrict__ tboxes, const int* __restrict__ tlabels,
    float* __restrict__ C)
{
    cost_tile(blockIdx.x, probs, pboxes, tboxes, tlabels, C);
}

// ===========================================================================
// fallback (round-1 proven path, reads C, no workspace) if ws too small
// ===========================================================================
__global__ __launch_bounds__(64) void hungarian_kernel_fb(
    const float* __restrict__ C, float* __restrict__ pred_out,
    float* __restrict__ tgt_out)
{
    __shared__ float  cost[NR * M];
    __shared__ double v[M + 1], minv[M + 1], u[NR + 1];
    __shared__ int    p[M + 1], way[M + 1];
    __shared__ unsigned char used[M + 1];
    const int b = blockIdx.x;
    const int tid = threadIdx.x;
    const double INF = 1e18;
    for (int e = tid; e < NR * M; e += 64) {
        const int q = e >> 6, i = e & 63;
        cost[i * M + q] = C[(size_t)b * Q * T + (size_t)q * T + b * TPER + i];
    }
    for (int j = tid; j <= M; j += 64) { v[j] = 0.0; p[j] = 0; }
    for (int j = tid; j <= NR; j += 64) u[j] = 0.0;
    __syncthreads();
    for (int i = 1; i <= NR; ++i) {
        if (tid == 0) p[0] = i;
        for (int j = tid; j <= M; j += 64) { minv[j] = INF; used[j] = 0; }
        __syncthreads();
        int j0 = 0;
        while (true) {
            if (tid == 0) used[j0] = 1;
            __syncthreads();
            const int    i0  = p[j0];
            const double ui0 = u[i0];
            const float* crow = &cost[(i0 - 1) * M];
            double lmin = INF; int lidx = M + 1;
            for (int j = tid + 1; j <= M; j += 64) {
                if (!used[j]) {
                    double mv = minv[j];
                    const double cj = (double)crow[j - 1] - ui0 - v[j];
                    if (cj < mv) { mv = cj; minv[j] = cj; way[j] = j0; }
                    if (mv < lmin) { lmin = mv; lidx = j; }
                }
            }
#pragma unroll
            for (int off = 32; off > 0; off >>= 1) {
                const double oval = __shfl_down(lmin, off);
                const int    oidx = __shfl_down(lidx, off);
                if (oval < lmin || (oval == lmin && oidx < lidx)) { lmin = oval; lidx = oidx; }
            }
            const int    j1    = __shfl(lidx, 0);
            const double delta = __shfl(lmin, 0);
            __syncthreads();
            for (int j = tid; j <= M; j += 64) {
                if (used[j]) { u[p[j]] += delta; v[j] -= delta; }
                else          minv[j] -= delta;
            }
            __syncthreads();
            j0 = j1;
            if (p[j0] == 0) break;
        }
        if (tid == 0) {
            int jj = j0;
            while (jj) { const int j1 = way[jj]; p[jj] = p[j1]; jj = j1; }
        }
        __syncthreads();
    }
    if (tid == 0) {
        int kk = 0;
        for (int j = 1; j <= M; ++j) {
            if (p[j] > 0) {
                pred_out[b * TPER + kk] = (float)(j - 1);
                tgt_out [b * TPER + kk] = (float)(p[j] - 1);
                ++kk;
            }
        }
    }
}

extern "C" void kernel_launch(void* const* d_in, const int* in_sizes, int n_in,
                              void* d_out, int out_size, void* d_ws, size_t ws_size,
                              hipStream_t stream) {
    const float* probs   = (const float*)d_in[0];   // [64,300,91]
    const float* pboxes  = (const float*)d_in[1];   // [64,300,4]
    const float* tboxes  = (const float*)d_in[2];   // [4096,4]
    const int*   tlabels = (const int*)  d_in[3];   // [4096]

    float* C    = (float*)d_out;                    // [64,300,4096]
    float* pred = C + (size_t)BS * Q * T;           // [64,64] as float
    float* tgt  = pred + (size_t)BS * TPER;         // [64,64] as float

    const size_t ws_needed = (size_t)BS * NR * WS_STRIDE * sizeof(float);
    if (ws_size >= ws_needed) {
        hipLaunchKernelGGL(fused_kernel, dim3(BS + BS * Q / 4), dim3(256), 0, stream,
                           probs, pboxes, tboxes, tlabels, C, pred, tgt, (float*)d_ws);
    } else {
        hipLaunchKernelGGL(cost_kernel, dim3(BS * Q / 4), dim3(256), 0, stream,
                           probs, pboxes, tboxes, tlabels, C);
        hipLaunchKernelGGL(hungarian_kernel_fb, dim3(BS), dim3(64), 0, stream,
                           C, pred, tgt);
    }
}